// Round 24
// baseline (21.998 us; speedup 1.0000x reference)
//
#include <hip/hip_runtime.h>
#include <hip/hip_bf16.h>

typedef __attribute__((ext_vector_type(8))) short bf16x8;
typedef __attribute__((ext_vector_type(4))) float f32x4;

#define NPIX 32768

__device__ __forceinline__ ushort f2bf(float f) {
    __hip_bfloat16 h = __float2bfloat16(f);   // single v_cvt, RNE
    ushort u; __builtin_memcpy(&u, &h, 2);
    return u;
}

// R21 split into WAVE PAIRS: same block (2 rows / 128 px), 1024 threads /
// 16 waves; a PAIR of waves shares each 16-px tile. Total instruction count
// ~unchanged (no tile waste, no weight re-streaming):
//   staging: 8 rows/wave (was 16) | GEMM1: d-halves, 16 MFMA/wave (was 32)
//   GEMM2: e-tiles 5/4 per wave (was 9) | invol: 8 px/wave (was 16)
// -> 4 waves/SIMD (was 2): doubles stall coverage at constant work.
// Costs: 2 extra block barriers (hs, ks now pair-shared).
// Arena per pair (11776 B): hs bf16 [16][128B] @0 | xs bf16 [16][512B]
//   @2048 | ks f32 [16][148] @2048 (aliases xs ONLY -- xs is dead block-
//   wide after barrier 1; ks must NOT alias hs, still read in GEMM2).
// LDS: 8 pairs x 11776 @0 | W1s 32768 @94208 | W2s 18432 @126976
//   => 145408 B, 1 block/CU (16 waves/CU).
// XCD k owns image k for halo L2 locality.
__global__ __launch_bounds__(1024, 1) void fused_kernel(
        const float* __restrict__ x,
        const float* __restrict__ W1, const float* __restrict__ b1,
        const float* __restrict__ gamma, const float* __restrict__ beta,
        const float* __restrict__ mean, const float* __restrict__ var,
        const float* __restrict__ W2, const float* __restrict__ b2,
        float* __restrict__ ker, float* __restrict__ out) {
    __shared__ __align__(16) char smem[145408];
    const int t = threadIdx.x;
    const int wv = t >> 6, ln = t & 63;
    const int pair = wv >> 1, sub = wv & 1;
    char* arena = smem + pair * 11776;           // shared by the wave pair
    char* w1s   = smem + 94208;                  // block-shared packed W1
    char* w2s   = smem + 126976;                 // block-shared packed W2
    const int bid = (int)blockIdx.x;
    const int img = bid & 7;                     // XCD k <- image k
    const int rp  = bid >> 3;                    // row pair 0..31
    const int i   = rp * 2 + (pair >> 2);        // image row of this pair
    const int lb  = img * 64 + i;                // b*64 + i
    const int j0p = (pair & 3) * 16;             // pair's first column
    const int pwp = lb * 64 + j0p;               // pair's first pixel
    const int j0  = j0p + sub * 8;               // wave's invol column base
    const int r16 = ln & 15, g = ln >> 4;

    // ---- repack W1 -> w1s (2048 x 16B chunks, 2 per thread) ----
    #pragma unroll
    for (int m = 0; m < 2; m++) {
        int idx = m * 1024 + t;
        int ln2 = idx & 63, dt = (idx >> 6) & 3, kk = idx >> 8;
        int d = dt * 16 + (ln2 & 15);
        float sc = gamma[d] * rsqrtf(var[d] + 1e-3f);
        int cbase = kk * 32 + (ln2 >> 4) * 8;
        ushort tmp[8];
        #pragma unroll
        for (int cc = 0; cc < 8; cc++)
            tmp[cc] = f2bf(W1[(cbase + cc) * 64 + d] * sc);
        __builtin_memcpy(w1s + idx * 16, tmp, 16);
    }
    // ---- repack W2 -> w2s (1152 x 16B chunks) ----
    {
        int idx = t;
        if (idx < 1152) {
            int ln2 = idx & 63, rem = idx >> 6;   // rem < 18
            int et = rem % 9, kk = rem / 9;
            int e = et * 16 + (ln2 & 15);
            int dbase = kk * 32 + (ln2 >> 4) * 8;
            ushort tmp[8];
            #pragma unroll
            for (int cc = 0; cc < 8; cc++)
                tmp[cc] = f2bf(W2[(dbase + cc) * 144 + e]);
            __builtin_memcpy(w2s + idx * 16, tmp, 16);
        }
        idx = 1024 + t;
        if (idx < 1152) {
            int ln2 = idx & 63, rem = idx >> 6;
            int et = rem % 9, kk = rem / 9;
            int e = et * 16 + (ln2 & 15);
            int dbase = kk * 32 + (ln2 >> 4) * 8;
            ushort tmp[8];
            #pragma unroll
            for (int cc = 0; cc < 8; cc++)
                tmp[cc] = f2bf(W2[(dbase + cc) * 144 + e]);
            __builtin_memcpy(w2s + idx * 16, tmp, 16);
        }
    }
    // ---- per-thread BN-folded bias for this wave's d-half ----
    float b1fv[2];
    #pragma unroll
    for (int dtl = 0; dtl < 2; dtl++) {
        int d = (sub * 2 + dtl) * 16 + r16;
        float sc = gamma[d] * rsqrtf(var[d] + 1e-3f);
        b1fv[dtl] = (b1[d] - mean[d]) * sc + beta[d];
    }

    // ---- stage 8 x-rows per wave (pair covers 16): f32->bf16, swizzled ----
    {
        const float4* xg = (const float4*)(x + (size_t)(pwp + sub * 8) * 256);
        #pragma unroll
        for (int it = 0; it < 8; it++) {
            int row = sub * 8 + it;               // row&7 == it (it<8)
            float4 v = xg[it * 64 + ln];
            ushort4 b4; b4.x = f2bf(v.x); b4.y = f2bf(v.y);
            b4.z = f2bf(v.z); b4.w = f2bf(v.w);
            int bcol = (ln * 8) ^ ((it & 7) << 4);
            *(ushort4*)(arena + 2048 + row * 512 + bcol) = b4;
        }
    }
    __syncthreads();   // barrier 0: w1s/w2s + pair xs complete

    // ---- GEMM1: 16 px x 32 d (this wave's d-half); 16 MFMA ----
    f32x4 acc[2];
    #pragma unroll
    for (int dtl = 0; dtl < 2; dtl++) {
        float bv = b1fv[dtl];
        acc[dtl] = (f32x4){bv, bv, bv, bv};
    }
    #pragma unroll
    for (int kk = 0; kk < 8; kk++) {
        int bcA = (kk * 64 + g * 16) ^ ((r16 & 7) << 4);
        bf16x8 av = *(const bf16x8*)(arena + 2048 + r16 * 512 + bcA);
        #pragma unroll
        for (int dtl = 0; dtl < 2; dtl++) {
            int dt = sub * 2 + dtl;
            bf16x8 bv = *(const bf16x8*)(w1s + (((kk * 4 + dt) << 6) + ln) * 16);
            acc[dtl] = __builtin_amdgcn_mfma_f32_16x16x32_bf16(av, bv, acc[dtl], 0, 0, 0);
        }
    }

    // relu -> bf16 -> hs (arena+0, this wave's d-half, all 16 rows)
    #pragma unroll
    for (int dtl = 0; dtl < 2; dtl++) {
        int dt = sub * 2 + dtl;
        #pragma unroll
        for (int r = 0; r < 4; r++) {
            int q = g * 4 + r;
            int bcol = ((dt * 16 + r16) * 2) ^ ((q & 7) << 4);
            *(ushort*)(arena + q * 128 + bcol) = f2bf(fmaxf(acc[dtl][r], 0.f));
        }
    }

    // ---- invol window preload (global-only; hides under barrier+GEMM2) ----
    const f32x4* xv4 = (const f32x4*)x;
    const f32x4 z4 = {0.f, 0.f, 0.f, 0.f};
    f32x4 wa[3], wb[3], wc[3], wd[3];   // cols j-1, j, j+1, j+2
    #pragma unroll
    for (int r = 0; r < 3; r++) {
        int row = i + r - 1;
        bool rv = (unsigned)row < 64u;
        const size_t rb = (size_t)(lb + r - 1) * 64;
        wa[r] = (rv && j0 > 0) ? xv4[(rb + (j0 - 1)) * 64 + ln] : z4;
        wb[r] = rv ? xv4[(rb + j0) * 64 + ln] : z4;
        wc[r] = rv ? xv4[(rb + j0 + 1) * 64 + ln] : z4;   // j0+1 <= 57 < 64
        wd[r] = rv ? xv4[(rb + j0 + 2) * 64 + ln] : z4;   // j0+2 <= 58 < 64
    }

    __syncthreads();   // barrier 1: hs complete (both d-halves)

    // ---- GEMM2 + ks write: this wave's e-tiles (sub0: 0..4, sub1: 5..8) ----
    float* ksf = (float*)(arena + 2048);              // [16][148], aliases xs
    if (sub == 0) {
        f32x4 acc2[5];
        #pragma unroll
        for (int etl = 0; etl < 5; etl++) {
            float bv = b2[etl * 16 + r16];
            acc2[etl] = (f32x4){bv, bv, bv, bv};
        }
        #pragma unroll
        for (int kk = 0; kk < 2; kk++) {
            int bcA = (kk * 64 + g * 16) ^ ((r16 & 7) << 4);
            bf16x8 av = *(const bf16x8*)(arena + r16 * 128 + bcA);
            #pragma unroll
            for (int etl = 0; etl < 5; etl++) {
                bf16x8 bv = *(const bf16x8*)(w2s + (((kk * 9 + etl) << 6) + ln) * 16);
                acc2[etl] = __builtin_amdgcn_mfma_f32_16x16x32_bf16(av, bv, acc2[etl], 0, 0, 0);
            }
        }
        #pragma unroll
        for (int etl = 0; etl < 5; etl++) {
            #pragma unroll
            for (int r = 0; r < 4; r++) {
                int q = g * 4 + r;
                ksf[q * 148 + etl * 16 + r16] = acc2[etl][r];
            }
        }
    } else {
        f32x4 acc2[4];
        #pragma unroll
        for (int etl = 0; etl < 4; etl++) {
            float bv = b2[(5 + etl) * 16 + r16];
            acc2[etl] = (f32x4){bv, bv, bv, bv};
        }
        #pragma unroll
        for (int kk = 0; kk < 2; kk++) {
            int bcA = (kk * 64 + g * 16) ^ ((r16 & 7) << 4);
            bf16x8 av = *(const bf16x8*)(arena + r16 * 128 + bcA);
            #pragma unroll
            for (int etl = 0; etl < 4; etl++) {
                bf16x8 bv = *(const bf16x8*)(w2s + (((kk * 9 + 5 + etl) << 6) + ln) * 16);
                acc2[etl] = __builtin_amdgcn_mfma_f32_16x16x32_bf16(av, bv, acc2[etl], 0, 0, 0);
            }
        }
        #pragma unroll
        for (int etl = 0; etl < 4; etl++) {
            #pragma unroll
            for (int r = 0; r < 4; r++) {
                int q = g * 4 + r;
                ksf[q * 148 + (5 + etl) * 16 + r16] = acc2[etl][r];
            }
        }
    }

    __syncthreads();   // barrier 2: ks complete (both e-halves)

    // ---- involution: 8 px/wave, 4-column shift window, prefetch depth 2 ----
    const int s4 = (ln & 3) * 4;
    #pragma unroll
    for (int pp = 0; pp < 8; pp++) {
        const int j = j0 + pp;
        const float* kp = ksf + (sub * 8 + pp) * 148 + s4;
        f32x4 o = {0.f, 0.f, 0.f, 0.f};
        #pragma unroll
        for (int r = 0; r < 3; r++) {
            o += (*(const f32x4*)(kp + (r * 3 + 0) * 16)) * wa[r];
            o += (*(const f32x4*)(kp + (r * 3 + 1) * 16)) * wb[r];
            o += (*(const f32x4*)(kp + (r * 3 + 2) * 16)) * wc[r];
        }
        __builtin_nontemporal_store(o, &((f32x4*)out)[(size_t)(lb * 64 + j) * 64 + ln]);
        #pragma unroll
        for (int r = 0; r < 3; r++) { wa[r] = wb[r]; wb[r] = wc[r]; wc[r] = wd[r]; }
        if (pp < 6) {
            const int jn = j + 3;                      // consumed at pp+2
            const bool cv = jn < 64;
            #pragma unroll
            for (int r = 0; r < 3; r++) {
                int row = i + r - 1;
                bool rv = (unsigned)row < 64u;
                wd[r] = (rv && cv)
                    ? xv4[((size_t)(lb + r - 1) * 64 + jn) * 64 + ln] : z4;
            }
        }
    }

    // ---- coalesced ker epilogue: wave's 8 px rows -> contiguous NT stores ----
    {
        float* kerW = ker + (size_t)(pwp + sub * 8) * 144;  // 1152 f32 = 288 x4
        #pragma unroll
        for (int m = 0; m < 5; m++) {
            int fidx = m * 64 + ln;
            if (fidx < 288) {
                int row  = fidx / 36;        // local px row 0..7
                int col4 = fidx - row * 36;  // f32x4 within row (144/4=36)
                f32x4 v = *(const f32x4*)(ksf + (sub * 8 + row) * 148 + col4 * 4);
                __builtin_nontemporal_store(v, (f32x4*)(kerW + fidx * 4));
            }
        }
    }
}

extern "C" void kernel_launch(void* const* d_in, const int* in_sizes, int n_in,
                              void* d_out, int out_size, void* d_ws, size_t ws_size,
                              hipStream_t stream) {
    const float* x     = (const float*)d_in[0];
    const float* W1    = (const float*)d_in[1];
    const float* b1    = (const float*)d_in[2];
    const float* gamma = (const float*)d_in[3];
    const float* beta  = (const float*)d_in[4];
    const float* mmean = (const float*)d_in[5];
    const float* mvar  = (const float*)d_in[6];
    const float* W2    = (const float*)d_in[7];
    const float* b2    = (const float*)d_in[8];

    float* out_main = (float*)d_out;                 // (B,H,W,C)   = 8388608 f32
    float* out_ker  = (float*)d_out + 8388608;       // (B,H,W,144) = 4718592 f32

    fused_kernel<<<NPIX / 128, 1024, 0, stream>>>(
        x, W1, b1, gamma, beta, mmean, mvar, W2, b2, out_ker, out_main);
}